// Round 4
// baseline (8458.649 us; speedup 1.0000x reference)
//
#include <hip/hip_runtime.h>
#include <math.h>

#define TT   64    // T_in == T_out
#define BB   64    // batch
#define HH   256   // hidden
#define VV   32000 // vocab
#define NG   1024  // 4*H gate rows
#define KK   256   // GEMM K (always H)

typedef __bf16 bf16x8 __attribute__((ext_vector_type(8)));
typedef float  f32x4  __attribute__((ext_vector_type(4)));

// ---------------- embedding gather ----------------
__global__ void embed_kernel(const int* __restrict__ tok, const float* __restrict__ tab,
                             float* __restrict__ X, int shifted) {
  int blk = blockIdx.x;          // t*B + b
  int t = blk >> 6, b = blk & 63;
  int id;
  if (shifted) id = (t == 0) ? 0 : tok[(t - 1) * BB + b];
  else         id = tok[t * BB + b];
  const float4* src = (const float4*)(tab + (long)id * HH);
  float4* dst = (float4*)(X + (long)blk * HH);
  dst[threadIdx.x] = src[threadIdx.x];   // 64 threads * float4 = 256 floats
}

// ---------------- weight packing ----------------
// Row permutation r' = 4*j + g  <->  r = g*256 + j  (gate-interleave per hidden unit)
__global__ void pack_wih(const float* __restrict__ eW, const float* __restrict__ dW,
                         const float* __restrict__ ebi, const float* __restrict__ ebh,
                         const float* __restrict__ dbi, const float* __restrict__ dbh,
                         float* __restrict__ Wpk, float* __restrict__ bpk) {
  int L = blockIdx.y;            // 0..5
  int rp = blockIdx.x;           // 0..1023
  int j = rp >> 2, g = rp & 3;
  int r = g * HH + j;
  const float* src = (L < 3 ? eW + (long)L * NG * HH : dW + (long)(L - 3) * NG * HH) + (long)r * HH;
  float* dst = Wpk + ((long)L * NG + rp) * HH;
  ((float4*)dst)[threadIdx.x] = ((const float4*)src)[threadIdx.x];  // 64 thr * float4
  if (threadIdx.x == 0) {
    const float* bi = (L < 3 ? ebi + L * NG : dbi + (L - 3) * NG);
    const float* bh = (L < 3 ? ebh + L * NG : dbh + (L - 3) * NG);
    bpk[(long)L * NG + rp] = bi[r] + bh[r];
  }
}

// WT[L][k][r'] = Whh[L][g*256+j][k]  (transposed + gate-interleaved)
__global__ void pack_whhT(const float* __restrict__ eW, const float* __restrict__ dW,
                          float* __restrict__ WT) {
  int L = blockIdx.y;            // 0..5
  int k = blockIdx.x;            // 0..255
  const float* src = (L < 3 ? eW + (long)L * NG * HH : dW + (long)(L - 3) * NG * HH);
  float* dst = WT + ((long)L * HH + k) * NG;
  int t = threadIdx.x;           // 0..255 -> j = t, g = 0..3
  float4 v;
  v.x = src[((long)(0 * HH + t)) * HH + k];
  v.y = src[((long)(1 * HH + t)) * HH + k];
  v.z = src[((long)(2 * HH + t)) * HH + k];
  v.w = src[((long)(3 * HH + t)) * HH + k];
  ((float4*)dst)[t] = v;
}

// ---------------- helpers ----------------
__device__ __forceinline__ unsigned long long shfl_xor_u64(unsigned long long v, int m) {
  unsigned lo = (unsigned)v, hi = (unsigned)(v >> 32);
  lo = __shfl_xor(lo, m);
  hi = __shfl_xor(hi, m);
  return ((unsigned long long)hi << 32) | lo;
}

__device__ __forceinline__ unsigned bf_rne(float x) {  // fp32 -> bf16 bits (RNE)
  unsigned u = __float_as_uint(x);
  return (u + 0x7FFFu + ((u >> 16) & 1u)) >> 16;
}
// split x ~= hi + lo, both bf16 (residual ~2^-18 |x|)
__device__ __forceinline__ void bf_split4(float4 v, short4& hi, short4& lo) {
  unsigned h0 = bf_rne(v.x), h1 = bf_rne(v.y), h2 = bf_rne(v.z), h3 = bf_rne(v.w);
  hi = make_short4((short)h0, (short)h1, (short)h2, (short)h3);
  lo = make_short4((short)bf_rne(v.x - __uint_as_float(h0 << 16)),
                   (short)bf_rne(v.y - __uint_as_float(h1 << 16)),
                   (short)bf_rne(v.z - __uint_as_float(h2 << 16)),
                   (short)bf_rne(v.w - __uint_as_float(h3 << 16)));
}

// ---------------- split-bf16 MFMA GEMM: C[M,N] = A[M,256]*B[N,256]^T + bias ----------------
// 128x128 tile, 256 threads = 4 waves (2x2), each wave 64x64 via 4x4 frags of 16x16x32.
// fp32 accuracy via 3 passes: Ahi*Bhi + Alo*Bhi + Ahi*Blo (err ~3e-6, fp32-reorder class).
__global__ __launch_bounds__(256) void gemm_mfma(
    const float* __restrict__ A, const float* __restrict__ B,
    const float* __restrict__ bias, float* __restrict__ C,
    int N, unsigned long long* __restrict__ amax) {
  __shared__ short lds[4 * 128 * 64];       // Ah | Al | Bh | Bl = 64 KB
  short* Ah = lds;
  short* Al = Ah + 128 * 64;
  short* Bh = Al + 128 * 64;
  short* Bl = Bh + 128 * 64;
  const int t = threadIdx.x;
  const int lane = t & 63;
  const int wid = t >> 6;
  const int wm = wid >> 1, wn = wid & 1;    // 2x2 wave grid
  const int lx = lane & 15, lg = lane >> 4;
  const int m0 = blockIdx.y * 128, n0 = blockIdx.x * 128;
  f32x4 acc[4][4] = {};                     // [mf][nf], D frag: col=lane&15, row=lg*4+reg

  for (int kc = 0; kc < KK; kc += 64) {
    // ---- stage 128x64 fp32 chunk of A and B -> hi/lo bf16, swizzled ----
    #pragma unroll
    for (int p = 0; p < 8; p++) {
      int f   = t + 256 * p;        // float4 index in the 128x16 float4 tile
      int row = f >> 4;             // 0..127
      int c4  = f & 15;             // float4 within row (coalesced across lanes)
      float4 av = *(const float4*)(A + (long)(m0 + row) * KK + kc + c4 * 4);
      float4 bv = *(const float4*)(B + (long)(n0 + row) * KK + kc + c4 * 4);
      int boff = row * 128 + ((c4 * 8) ^ ((row & 7) << 4));  // byte offset, 8B piece
      short4 h4, l4;
      bf_split4(av, h4, l4);
      *(short4*)((char*)Ah + boff) = h4;
      *(short4*)((char*)Al + boff) = l4;
      bf_split4(bv, h4, l4);
      *(short4*)((char*)Bh + boff) = h4;
      *(short4*)((char*)Bl + boff) = l4;
    }
    __syncthreads();
    #pragma unroll
    for (int ks = 0; ks < 2; ks++) {        // two K=32 steps per chunk
      bf16x8 ah[4], al[4], bh[4], bl[4];
      #pragma unroll
      for (int q = 0; q < 4; q++) {
        int ra = wm * 64 + q * 16 + lx;
        int ca = (ks * 64 + lg * 16) ^ ((ra & 7) << 4);
        ah[q] = *(const bf16x8*)((const char*)Ah + ra * 128 + ca);
        al[q] = *(const bf16x8*)((const char*)Al + ra * 128 + ca);
        int rb = wn * 64 + q * 16 + lx;
        int cb = (ks * 64 + lg * 16) ^ ((rb & 7) << 4);
        bh[q] = *(const bf16x8*)((const char*)Bh + rb * 128 + cb);
        bl[q] = *(const bf16x8*)((const char*)Bl + rb * 128 + cb);
      }
      #pragma unroll
      for (int mf = 0; mf < 4; mf++)
        #pragma unroll
        for (int nf = 0; nf < 4; nf++) {
          acc[mf][nf] = __builtin_amdgcn_mfma_f32_16x16x32_bf16(ah[mf], bh[nf], acc[mf][nf], 0, 0, 0);
          acc[mf][nf] = __builtin_amdgcn_mfma_f32_16x16x32_bf16(al[mf], bh[nf], acc[mf][nf], 0, 0, 0);
          acc[mf][nf] = __builtin_amdgcn_mfma_f32_16x16x32_bf16(ah[mf], bl[nf], acc[mf][nf], 0, 0, 0);
        }
    }
    __syncthreads();
  }

  // ---- epilogue: bias, store, fused argmax ----
  float bv[4];
  #pragma unroll
  for (int nf = 0; nf < 4; nf++) bv[nf] = bias[n0 + wn * 64 + nf * 16 + lx];
  #pragma unroll
  for (int mf = 0; mf < 4; mf++) {
    #pragma unroll
    for (int r = 0; r < 4; r++) {
      int m = m0 + wm * 64 + mf * 16 + lg * 4 + r;
      float best = -3.0e38f; int bi = 0;
      #pragma unroll
      for (int nf = 0; nf < 4; nf++) {
        int col = n0 + wn * 64 + nf * 16 + lx;
        float o = acc[mf][nf][r] + bv[nf];
        C[(long)m * N + col] = o;
        if (o > best) { best = o; bi = col; }   // strict > keeps lowest col on tie
      }
      if (amax) {
        unsigned uo = __float_as_uint(best);
        uo = (uo >> 31) ? ~uo : (uo | 0x80000000u);   // orderable float bits
        unsigned long long key = ((unsigned long long)uo << 32) | (unsigned)(0xFFFFFFFFu - bi);
        #pragma unroll
        for (int s2 = 1; s2 < 16; s2 <<= 1) {   // reduce over the 16-lane col group
          unsigned long long o2 = shfl_xor_u64(key, s2);
          if (o2 > key) key = o2;
        }
        if (lx == 0) amax[(long)m * 500 + blockIdx.x * 2 + wn] = key;
      }
    }
  }
}

// reduce per-row segment keys -> float index
__global__ void argmax_fin(const unsigned long long* __restrict__ amax,
                           float* __restrict__ out1, int ntiles) {
  int row = blockIdx.x;
  int t = threadIdx.x;   // 64
  unsigned long long key = 0ull;
  for (int c = t; c < ntiles; c += 64) {
    unsigned long long k = amax[(long)row * ntiles + c];
    if (k > key) key = k;
  }
  #pragma unroll
  for (int s = 1; s < 64; s <<= 1) {
    unsigned long long o = shfl_xor_u64(key, s);
    if (o > key) key = o;
  }
  if (t == 0) out1[row] = (float)(0xFFFFFFFFu - (unsigned)(key & 0xFFFFFFFFu));
}

// ---------------- weight-stationary LSTM recurrence: 1 block per batch, Whh in VGPRs ---------
// 1024 threads (16 waves, 1 block/CU). Thread (ks=tid>>7, rw=tid&127) holds an
// 8-row x 32-k slice of Whh^T in registers (256 VGPR), loaded ONCE per layer — removes the
// 1 MB/step/CU L2 weight re-stream that bounded the round-1 kernel (8.2 us/step).
// Per step: 8x ds_read_b128 of the wave-uniform h slice (broadcast), 256 FMA,
// partials -> LDS (stride-72 pad), threads 0..255 reduce 8 x f32x4 (all 4 gates of unit j
// land in one thread), pointwise with c in register, h -> LDS + global. 2 syncthreads/step,
// NO grid sync (round-3's cross-XCD barrier cost 14.9 us/step + L2-flush refetch storm).
__global__ __launch_bounds__(1024, 4) void lstm_unit(
    const float* __restrict__ G,      // [T*B][1024] pre-gates incl. biases
    const float* __restrict__ WTl,    // [256][1024] packed Whh^T (k-major, r'=4j+g)
    const float* __restrict__ h0, int h0s,
    const float* __restrict__ c0, int c0s,
    float* __restrict__ Hout,         // [T*B][256]
    float* __restrict__ hfin, float* __restrict__ cfin) {
  __shared__ float h_sh[HH];
  __shared__ float part2[128 * 72];   // [rw][ks*8 + rr], 36 KB, stride-72 pad
  const int tid = threadIdx.x;
  const int b = blockIdx.x;
  const int ks = tid >> 7;            // k-slice 0..7 (32 k each); wave-uniform
  const int rw = tid & 127;           // row-group: gate rows rw*8 .. rw*8+7 (units 2rw,2rw+1)

  // --- preload Whh^T slice into registers: w[k'][half], rows rw*8+0..3 / +4..7 ---
  f32x4 w[32][2];
  #pragma unroll
  for (int k = 0; k < 32; k++) {
    const float* wp = WTl + (long)(ks * 32 + k) * NG + rw * 8;
    w[k][0] = *(const f32x4*)wp;
    w[k][1] = *(const f32x4*)(wp + 4);
  }

  // --- init state ---
  float c_state = 0.f;
  if (tid < HH) {
    h_sh[tid] = h0[(long)b * h0s + tid];
    c_state = c0[(long)b * c0s + tid];
  }
  __syncthreads();

  for (int t = 0; t < TT; t++) {
    // prefetch pre-gates for the pointwise phase (latency hidden under FMA loop)
    f32x4 g4 = {0.f, 0.f, 0.f, 0.f};
    if (tid < HH)
      g4 = *(const f32x4*)(G + ((long)t * BB + b) * NG + tid * 4);

    // --- partial gates: 8 rows x 32-k slice, h read is wave-uniform broadcast ---
    f32x4 a0 = {0.f, 0.f, 0.f, 0.f}, a1 = {0.f, 0.f, 0.f, 0.f};
    #pragma unroll
    for (int k4 = 0; k4 < 8; k4++) {
      f32x4 h4 = *(const f32x4*)&h_sh[ks * 32 + k4 * 4];
      a0 += w[k4 * 4 + 0][0] * h4.x; a1 += w[k4 * 4 + 0][1] * h4.x;
      a0 += w[k4 * 4 + 1][0] * h4.y; a1 += w[k4 * 4 + 1][1] * h4.y;
      a0 += w[k4 * 4 + 2][0] * h4.z; a1 += w[k4 * 4 + 2][1] * h4.z;
      a0 += w[k4 * 4 + 3][0] * h4.w; a1 += w[k4 * 4 + 3][1] * h4.w;
    }
    *(f32x4*)&part2[rw * 72 + ks * 8]     = a0;
    *(f32x4*)&part2[rw * 72 + ks * 8 + 4] = a1;
    __syncthreads();

    // --- reduce + pointwise: thread j (<256) owns unit j; its 4 gates are contiguous ---
    if (tid < HH) {
      f32x4 gs = g4;   // pre-gates (x*Wih^T + bih + bhh) from GEMM
      const int base = (tid >> 1) * 72 + (tid & 1) * 4;   // rows 4j..4j+3 partials
      #pragma unroll
      for (int kr = 0; kr < 8; kr++)
        gs += *(const f32x4*)&part2[base + kr * 8];
      float i_ = 1.f / (1.f + __expf(-gs.x));
      float f_ = 1.f / (1.f + __expf(-gs.y));
      float g_ = 2.f / (1.f + __expf(-2.f * gs.z)) - 1.f;
      float o_ = 1.f / (1.f + __expf(-gs.w));
      c_state = f_ * c_state + i_ * g_;
      float th = 2.f / (1.f + __expf(-2.f * c_state)) - 1.f;
      float hn = o_ * th;
      h_sh[tid] = hn;
      Hout[((long)t * BB + b) * HH + tid] = hn;
      if (t == TT - 1) {
        hfin[(long)b * HH + tid] = hn;
        cfin[(long)b * HH + tid] = c_state;
      }
    }
    __syncthreads();   // h_sh + part2 reuse safe for next step
  }
}

// ---------------- host orchestration ----------------
extern "C" void kernel_launch(void* const* d_in, const int* in_sizes, int n_in,
                              void* d_out, int out_size, void* d_ws, size_t ws_size,
                              hipStream_t stream) {
  const int*   inputs  = (const int*)d_in[0];
  const int*   targets = (const int*)d_in[1];
  const float* enc_emb = (const float*)d_in[2];
  const float* enc_Wih = (const float*)d_in[3];
  const float* enc_Whh = (const float*)d_in[4];
  const float* enc_bih = (const float*)d_in[5];
  const float* enc_bhh = (const float*)d_in[6];
  const float* hidden0 = (const float*)d_in[7];
  const float* cell0   = (const float*)d_in[8];
  const float* dec_emb = (const float*)d_in[9];
  const float* dec_Wih = (const float*)d_in[10];
  const float* dec_Whh = (const float*)d_in[11];
  const float* dec_bih = (const float*)d_in[12];
  const float* dec_bhh = (const float*)d_in[13];
  const float* fc_W    = (const float*)d_in[14];
  const float* fc_b    = (const float*)d_in[15];

  float* out0 = (float*)d_out;
  float* out1 = out0 + (long)TT * BB * VV;

  float* X   = (float*)d_ws;                 // [4096,256]   4 MB  (layer I/O sequence)
  float* G   = X   + (long)4096 * 256;       // [4096,1024] 16 MB  (pre-gates)
  float* Wpk = G   + (long)4096 * 1024;      // [6,1024,256] 6 MB
  float* WT  = Wpk + (long)6 * 1024 * 256;   // [6,256,1024] 6 MB
  float* bpk = WT  + (long)6 * 256 * 1024;   // [6,1024]
  float* hst = bpk + 6 * 1024;               // enc final h [3,64,256]
  float* cst = hst + 3 * 64 * 256;           // enc final c [3,64,256]
  float* hsc = cst + 3 * 64 * 256;           // dec scratch h
  float* csc = hsc + 64 * 256;               // dec scratch c
  unsigned long long* amax = (unsigned long long*)G;  // overlay: G dead before FC

  // weight packing (all 6 layers) + encoder embedding
  embed_kernel<<<4096, 64, 0, stream>>>(inputs, enc_emb, X, 0);
  pack_wih<<<dim3(1024, 6), 64, 0, stream>>>(enc_Wih, dec_Wih, enc_bih, enc_bhh,
                                             dec_bih, dec_bhh, Wpk, bpk);
  pack_whhT<<<dim3(256, 6), 256, 0, stream>>>(enc_Whh, dec_Whh, WT);

  // encoder: 3 layers
  for (int l = 0; l < 3; l++) {
    gemm_mfma<<<dim3(8, 32), 256, 0, stream>>>(X, Wpk + (long)l * NG * HH,
                                               bpk + l * NG, G, NG, nullptr);
    lstm_unit<<<64, 1024, 0, stream>>>(G, WT + (long)l * HH * NG,
                                       hidden0 + l * HH, 0, cell0 + l * HH, 0,
                                       X, hst + (long)l * BB * HH, cst + (long)l * BB * HH);
  }

  // decoder: teacher-forced input embedding, 3 layers seeded from encoder finals
  embed_kernel<<<4096, 64, 0, stream>>>(targets, dec_emb, X, 1);
  for (int l = 0; l < 3; l++) {
    gemm_mfma<<<dim3(8, 32), 256, 0, stream>>>(X, Wpk + (long)(3 + l) * NG * HH,
                                               bpk + (3 + l) * NG, G, NG, nullptr);
    lstm_unit<<<64, 1024, 0, stream>>>(G, WT + (long)(3 + l) * HH * NG,
                                       hst + (long)l * BB * HH, HH,
                                       cst + (long)l * BB * HH, HH,
                                       X, hsc, csc);
  }

  // FC head (split-bf16 MFMA) + fused per-64-col argmax, then finalize
  gemm_mfma<<<dim3(250, 32), 256, 0, stream>>>(X, fc_W, fc_b, out0, VV, amax);
  argmax_fin<<<4096, 64, 0, stream>>>(amax, out1, 500);
}

// Round 5
// 8105.227 us; speedup vs baseline: 1.0436x; 1.0436x over previous
//
#include <hip/hip_runtime.h>
#include <math.h>

#define TT   64    // T_in == T_out
#define BB   64    // batch
#define HH   256   // hidden
#define VV   32000 // vocab
#define NG   1024  // 4*H gate rows
#define KK   256   // GEMM K (always H)

typedef __bf16 bf16x8 __attribute__((ext_vector_type(8)));
typedef float  f32x4  __attribute__((ext_vector_type(4)));

// ---------------- embedding gather ----------------
__global__ void embed_kernel(const int* __restrict__ tok, const float* __restrict__ tab,
                             float* __restrict__ X, int shifted) {
  int blk = blockIdx.x;          // t*B + b
  int t = blk >> 6, b = blk & 63;
  int id;
  if (shifted) id = (t == 0) ? 0 : tok[(t - 1) * BB + b];
  else         id = tok[t * BB + b];
  const float4* src = (const float4*)(tab + (long)id * HH);
  float4* dst = (float4*)(X + (long)blk * HH);
  dst[threadIdx.x] = src[threadIdx.x];   // 64 threads * float4 = 256 floats
}

// ---------------- weight packing ----------------
// Row permutation r' = 4*j + g  <->  r = g*256 + j  (gate-interleave per hidden unit)
__global__ void pack_wih(const float* __restrict__ eW, const float* __restrict__ dW,
                         const float* __restrict__ ebi, const float* __restrict__ ebh,
                         const float* __restrict__ dbi, const float* __restrict__ dbh,
                         float* __restrict__ Wpk, float* __restrict__ bpk) {
  int L = blockIdx.y;            // 0..5
  int rp = blockIdx.x;           // 0..1023
  int j = rp >> 2, g = rp & 3;
  int r = g * HH + j;
  const float* src = (L < 3 ? eW + (long)L * NG * HH : dW + (long)(L - 3) * NG * HH) + (long)r * HH;
  float* dst = Wpk + ((long)L * NG + rp) * HH;
  ((float4*)dst)[threadIdx.x] = ((const float4*)src)[threadIdx.x];  // 64 thr * float4
  if (threadIdx.x == 0) {
    const float* bi = (L < 3 ? ebi + L * NG : dbi + (L - 3) * NG);
    const float* bh = (L < 3 ? ebh + L * NG : dbh + (L - 3) * NG);
    bpk[(long)L * NG + rp] = bi[r] + bh[r];
  }
}

// WT[L][k][r'] = Whh[L][g*256+j][k]  (transposed + gate-interleaved)
__global__ void pack_whhT(const float* __restrict__ eW, const float* __restrict__ dW,
                          float* __restrict__ WT) {
  int L = blockIdx.y;            // 0..5
  int k = blockIdx.x;            // 0..255
  const float* src = (L < 3 ? eW + (long)L * NG * HH : dW + (long)(L - 3) * NG * HH);
  float* dst = WT + ((long)L * HH + k) * NG;
  int t = threadIdx.x;           // 0..255 -> j = t, g = 0..3
  float4 v;
  v.x = src[((long)(0 * HH + t)) * HH + k];
  v.y = src[((long)(1 * HH + t)) * HH + k];
  v.z = src[((long)(2 * HH + t)) * HH + k];
  v.w = src[((long)(3 * HH + t)) * HH + k];
  ((float4*)dst)[t] = v;
}

// ---------------- helpers ----------------
__device__ __forceinline__ unsigned long long shfl_xor_u64(unsigned long long v, int m) {
  unsigned lo = (unsigned)v, hi = (unsigned)(v >> 32);
  lo = __shfl_xor(lo, m);
  hi = __shfl_xor(hi, m);
  return ((unsigned long long)hi << 32) | lo;
}

__device__ __forceinline__ unsigned bf_rne(float x) {  // fp32 -> bf16 bits (RNE)
  unsigned u = __float_as_uint(x);
  return (u + 0x7FFFu + ((u >> 16) & 1u)) >> 16;
}
// split x ~= hi + lo, both bf16 (residual ~2^-18 |x|)
__device__ __forceinline__ void bf_split4(float4 v, short4& hi, short4& lo) {
  unsigned h0 = bf_rne(v.x), h1 = bf_rne(v.y), h2 = bf_rne(v.z), h3 = bf_rne(v.w);
  hi = make_short4((short)h0, (short)h1, (short)h2, (short)h3);
  lo = make_short4((short)bf_rne(v.x - __uint_as_float(h0 << 16)),
                   (short)bf_rne(v.y - __uint_as_float(h1 << 16)),
                   (short)bf_rne(v.z - __uint_as_float(h2 << 16)),
                   (short)bf_rne(v.w - __uint_as_float(h3 << 16)));
}

// ---------------- split-bf16 MFMA GEMM: C[M,N] = A[M,256]*B[N,256]^T + bias ----------------
// 128x128 tile, 256 threads = 4 waves (2x2), each wave 64x64 via 4x4 frags of 16x16x32.
// fp32 accuracy via 3 passes: Ahi*Bhi + Alo*Bhi + Ahi*Blo (err ~3e-6, fp32-reorder class).
__global__ __launch_bounds__(256) void gemm_mfma(
    const float* __restrict__ A, const float* __restrict__ B,
    const float* __restrict__ bias, float* __restrict__ C,
    int N, unsigned long long* __restrict__ amax) {
  __shared__ short lds[4 * 128 * 64];       // Ah | Al | Bh | Bl = 64 KB
  short* Ah = lds;
  short* Al = Ah + 128 * 64;
  short* Bh = Al + 128 * 64;
  short* Bl = Bh + 128 * 64;
  const int t = threadIdx.x;
  const int lane = t & 63;
  const int wid = t >> 6;
  const int wm = wid >> 1, wn = wid & 1;    // 2x2 wave grid
  const int lx = lane & 15, lg = lane >> 4;
  const int m0 = blockIdx.y * 128, n0 = blockIdx.x * 128;
  f32x4 acc[4][4] = {};                     // [mf][nf], D frag: col=lane&15, row=lg*4+reg

  for (int kc = 0; kc < KK; kc += 64) {
    // ---- stage 128x64 fp32 chunk of A and B -> hi/lo bf16, swizzled ----
    #pragma unroll
    for (int p = 0; p < 8; p++) {
      int f   = t + 256 * p;        // float4 index in the 128x16 float4 tile
      int row = f >> 4;             // 0..127
      int c4  = f & 15;             // float4 within row (coalesced across lanes)
      float4 av = *(const float4*)(A + (long)(m0 + row) * KK + kc + c4 * 4);
      float4 bv = *(const float4*)(B + (long)(n0 + row) * KK + kc + c4 * 4);
      int boff = row * 128 + ((c4 * 8) ^ ((row & 7) << 4));  // byte offset, 8B piece
      short4 h4, l4;
      bf_split4(av, h4, l4);
      *(short4*)((char*)Ah + boff) = h4;
      *(short4*)((char*)Al + boff) = l4;
      bf_split4(bv, h4, l4);
      *(short4*)((char*)Bh + boff) = h4;
      *(short4*)((char*)Bl + boff) = l4;
    }
    __syncthreads();
    #pragma unroll
    for (int ks = 0; ks < 2; ks++) {        // two K=32 steps per chunk
      bf16x8 ah[4], al[4], bh[4], bl[4];
      #pragma unroll
      for (int q = 0; q < 4; q++) {
        int ra = wm * 64 + q * 16 + lx;
        int ca = (ks * 64 + lg * 16) ^ ((ra & 7) << 4);
        ah[q] = *(const bf16x8*)((const char*)Ah + ra * 128 + ca);
        al[q] = *(const bf16x8*)((const char*)Al + ra * 128 + ca);
        int rb = wn * 64 + q * 16 + lx;
        int cb = (ks * 64 + lg * 16) ^ ((rb & 7) << 4);
        bh[q] = *(const bf16x8*)((const char*)Bh + rb * 128 + cb);
        bl[q] = *(const bf16x8*)((const char*)Bl + rb * 128 + cb);
      }
      #pragma unroll
      for (int mf = 0; mf < 4; mf++)
        #pragma unroll
        for (int nf = 0; nf < 4; nf++) {
          acc[mf][nf] = __builtin_amdgcn_mfma_f32_16x16x32_bf16(ah[mf], bh[nf], acc[mf][nf], 0, 0, 0);
          acc[mf][nf] = __builtin_amdgcn_mfma_f32_16x16x32_bf16(al[mf], bh[nf], acc[mf][nf], 0, 0, 0);
          acc[mf][nf] = __builtin_amdgcn_mfma_f32_16x16x32_bf16(ah[mf], bl[nf], acc[mf][nf], 0, 0, 0);
        }
    }
    __syncthreads();
  }

  // ---- epilogue: bias, store, fused argmax ----
  float bv[4];
  #pragma unroll
  for (int nf = 0; nf < 4; nf++) bv[nf] = bias[n0 + wn * 64 + nf * 16 + lx];
  #pragma unroll
  for (int mf = 0; mf < 4; mf++) {
    #pragma unroll
    for (int r = 0; r < 4; r++) {
      int m = m0 + wm * 64 + mf * 16 + lg * 4 + r;
      float best = -3.0e38f; int bi = 0;
      #pragma unroll
      for (int nf = 0; nf < 4; nf++) {
        int col = n0 + wn * 64 + nf * 16 + lx;
        float o = acc[mf][nf][r] + bv[nf];
        C[(long)m * N + col] = o;
        if (o > best) { best = o; bi = col; }   // strict > keeps lowest col on tie
      }
      if (amax) {
        unsigned uo = __float_as_uint(best);
        uo = (uo >> 31) ? ~uo : (uo | 0x80000000u);   // orderable float bits
        unsigned long long key = ((unsigned long long)uo << 32) | (unsigned)(0xFFFFFFFFu - bi);
        #pragma unroll
        for (int s2 = 1; s2 < 16; s2 <<= 1) {   // reduce over the 16-lane col group
          unsigned long long o2 = shfl_xor_u64(key, s2);
          if (o2 > key) key = o2;
        }
        if (lx == 0) amax[(long)m * 500 + blockIdx.x * 2 + wn] = key;
      }
    }
  }
}

// reduce per-row segment keys -> float index
__global__ void argmax_fin(const unsigned long long* __restrict__ amax,
                           float* __restrict__ out1, int ntiles) {
  int row = blockIdx.x;
  int t = threadIdx.x;   // 64
  unsigned long long key = 0ull;
  for (int c = t; c < ntiles; c += 64) {
    unsigned long long k = amax[(long)row * ntiles + c];
    if (k > key) key = k;
  }
  #pragma unroll
  for (int s = 1; s < 64; s <<= 1) {
    unsigned long long o = shfl_xor_u64(key, s);
    if (o > key) key = o;
  }
  if (t == 0) out1[row] = (float)(0xFFFFFFFFu - (unsigned)(key & 0xFFFFFFFFu));
}

// ---------------- half-resident LSTM recurrence: 1 block/batch, 1024 threads ----------------
// R4 failed because 256 weight floats/thread exceeds the 256-VGPR VALU addressing limit ->
// whole array went to scratch (VGPR=64, 1.29 GB HBM/dispatch). This version holds HALF of
// Whh^T in registers as 32 NAMED f32x4 (128 floats/thread, SROA-trivial) and streams the
// other half from L2 each step (512 KB/CU/step, half of R1's measured 1 MB stream), software-
// pipelined through a single 16-reg buffer. Thread (ks=tid>>8, j=tid&255): unit j's 4 gate
// rows over k in [ks*64, ks*64+64); resident k = first 32, streamed k = last 32.
// Partials -> LDS [4][256] f32x4; threads 0..255 reduce 4 + pointwise; 2 syncthreads/step.
#define WD(i)  f32x4 wR##i = WT4[(long)(kbase + (i)) * 256 + j];
#define SD(i, koff) f32x4 sA##i = WT4[(long)(kbase + (koff) + (i)) * 256 + j];
#define SL(i, koff) sA##i = WT4[(long)(kbase + (koff) + (i)) * 256 + j];
#define RF(a0,a1,a2,a3,koff) { f32x4 h4 = *(const f32x4*)&h_sh[kbase + (koff)]; \
  acc += wR##a0 * h4.x; acc += wR##a1 * h4.y; acc += wR##a2 * h4.z; acc += wR##a3 * h4.w; }
#define SF(a0,a1,a2,a3,koff) { f32x4 h4 = *(const f32x4*)&h_sh[kbase + (koff)]; \
  acc += sA##a0 * h4.x; acc += sA##a1 * h4.y; acc += sA##a2 * h4.z; acc += sA##a3 * h4.w; }

__global__ __launch_bounds__(1024, 4) void lstm_unit(
    const float* __restrict__ G,      // [T*B][1024] pre-gates incl. biases
    const float* __restrict__ WTl,    // [256 k][1024 r'] packed Whh^T (r'=4j+g)
    const float* __restrict__ h0, int h0s,
    const float* __restrict__ c0, int c0s,
    float* __restrict__ Hout,         // [T*B][256]
    float* __restrict__ hfin, float* __restrict__ cfin) {
  __shared__ float h_sh[HH];
  __shared__ f32x4 part[4][HH];       // 16 KB
  const int tid = threadIdx.x;
  const int b = blockIdx.x;
  const int ks = tid >> 8;            // k-slice 0..3 (64 k each); wave-uniform
  const int j = tid & 255;            // hidden unit (4 gate rows 4j..4j+3)
  const int kbase = ks * 64;
  const f32x4* WT4 = (const f32x4*)WTl;   // [256 k][256 units] f32x4 (4 gates)

  // --- resident half: k in [kbase, kbase+32), 32 named f32x4 = 128 VGPR ---
  WD(0)  WD(1)  WD(2)  WD(3)  WD(4)  WD(5)  WD(6)  WD(7)
  WD(8)  WD(9)  WD(10) WD(11) WD(12) WD(13) WD(14) WD(15)
  WD(16) WD(17) WD(18) WD(19) WD(20) WD(21) WD(22) WD(23)
  WD(24) WD(25) WD(26) WD(27) WD(28) WD(29) WD(30) WD(31)

  // --- init state ---
  float c_state = 0.f;
  if (tid < HH) {
    h_sh[tid] = h0[(long)b * h0s + tid];
    c_state = c0[(long)b * c0s + tid];
  }
  __syncthreads();

  for (int t = 0; t < TT; t++) {
    // prefetch pre-gates for the pointwise phase (latency hidden under FMA phases)
    f32x4 g4 = {0.f, 0.f, 0.f, 0.f};
    if (tid < HH)
      g4 = *(const f32x4*)(G + ((long)t * BB + b) * NG + tid * 4);

    f32x4 acc = {0.f, 0.f, 0.f, 0.f};
    // phase 0: issue streamed chunk k+32..47; resident FMA k+0..15; consume
    SD(0,32)  SD(1,32)  SD(2,32)  SD(3,32)  SD(4,32)  SD(5,32)  SD(6,32)  SD(7,32)
    SD(8,32)  SD(9,32)  SD(10,32) SD(11,32) SD(12,32) SD(13,32) SD(14,32) SD(15,32)
    RF(0,1,2,3,0)     RF(4,5,6,7,4)     RF(8,9,10,11,8)    RF(12,13,14,15,12)
    SF(0,1,2,3,32)    SF(4,5,6,7,36)    SF(8,9,10,11,40)   SF(12,13,14,15,44)
    // phase 1: issue streamed chunk k+48..63; resident FMA k+16..31; consume
    SL(0,48)  SL(1,48)  SL(2,48)  SL(3,48)  SL(4,48)  SL(5,48)  SL(6,48)  SL(7,48)
    SL(8,48)  SL(9,48)  SL(10,48) SL(11,48) SL(12,48) SL(13,48) SL(14,48) SL(15,48)
    RF(16,17,18,19,16) RF(20,21,22,23,20) RF(24,25,26,27,24) RF(28,29,30,31,28)
    SF(0,1,2,3,48)     SF(4,5,6,7,52)     SF(8,9,10,11,56)   SF(12,13,14,15,60)

    part[ks][j] = acc;
    __syncthreads();

    // --- reduce + pointwise: thread j (<256) owns unit j ---
    if (tid < HH) {
      f32x4 gs = g4;
      gs += part[0][tid]; gs += part[1][tid]; gs += part[2][tid]; gs += part[3][tid];
      float i_ = 1.f / (1.f + __expf(-gs.x));
      float f_ = 1.f / (1.f + __expf(-gs.y));
      float g_ = 2.f / (1.f + __expf(-2.f * gs.z)) - 1.f;
      float o_ = 1.f / (1.f + __expf(-gs.w));
      c_state = f_ * c_state + i_ * g_;
      float th = 2.f / (1.f + __expf(-2.f * c_state)) - 1.f;
      float hn = o_ * th;
      h_sh[tid] = hn;
      Hout[((long)t * BB + b) * HH + tid] = hn;
      if (t == TT - 1) {
        hfin[(long)b * HH + tid] = hn;
        cfin[(long)b * HH + tid] = c_state;
      }
    }
    __syncthreads();   // h_sh + part reuse safe for next step
  }
}

// ---------------- host orchestration ----------------
extern "C" void kernel_launch(void* const* d_in, const int* in_sizes, int n_in,
                              void* d_out, int out_size, void* d_ws, size_t ws_size,
                              hipStream_t stream) {
  const int*   inputs  = (const int*)d_in[0];
  const int*   targets = (const int*)d_in[1];
  const float* enc_emb = (const float*)d_in[2];
  const float* enc_Wih = (const float*)d_in[3];
  const float* enc_Whh = (const float*)d_in[4];
  const float* enc_bih = (const float*)d_in[5];
  const float* enc_bhh = (const float*)d_in[6];
  const float* hidden0 = (const float*)d_in[7];
  const float* cell0   = (const float*)d_in[8];
  const float* dec_emb = (const float*)d_in[9];
  const float* dec_Wih = (const float*)d_in[10];
  const float* dec_Whh = (const float*)d_in[11];
  const float* dec_bih = (const float*)d_in[12];
  const float* dec_bhh = (const float*)d_in[13];
  const float* fc_W    = (const float*)d_in[14];
  const float* fc_b    = (const float*)d_in[15];

  float* out0 = (float*)d_out;
  float* out1 = out0 + (long)TT * BB * VV;

  float* X   = (float*)d_ws;                 // [4096,256]   4 MB  (layer I/O sequence)
  float* G   = X   + (long)4096 * 256;       // [4096,1024] 16 MB  (pre-gates)
  float* Wpk = G   + (long)4096 * 1024;      // [6,1024,256] 6 MB
  float* WT  = Wpk + (long)6 * 1024 * 256;   // [6,256,1024] 6 MB
  float* bpk = WT  + (long)6 * 256 * 1024;   // [6,1024]
  float* hst = bpk + 6 * 1024;               // enc final h [3,64,256]
  float* cst = hst + 3 * 64 * 256;           // enc final c [3,64,256]
  float* hsc = cst + 3 * 64 * 256;           // dec scratch h
  float* csc = hsc + 64 * 256;               // dec scratch c
  unsigned long long* amax = (unsigned long long*)G;  // overlay: G dead before FC

  // weight packing (all 6 layers) + encoder embedding
  embed_kernel<<<4096, 64, 0, stream>>>(inputs, enc_emb, X, 0);
  pack_wih<<<dim3(1024, 6), 64, 0, stream>>>(enc_Wih, dec_Wih, enc_bih, enc_bhh,
                                             dec_bih, dec_bhh, Wpk, bpk);
  pack_whhT<<<dim3(256, 6), 256, 0, stream>>>(enc_Whh, dec_Whh, WT);

  // encoder: 3 layers
  for (int l = 0; l < 3; l++) {
    gemm_mfma<<<dim3(8, 32), 256, 0, stream>>>(X, Wpk + (long)l * NG * HH,
                                               bpk + l * NG, G, NG, nullptr);
    lstm_unit<<<64, 1024, 0, stream>>>(G, WT + (long)l * HH * NG,
                                       hidden0 + l * HH, 0, cell0 + l * HH, 0,
                                       X, hst + (long)l * BB * HH, cst + (long)l * BB * HH);
  }

  // decoder: teacher-forced input embedding, 3 layers seeded from encoder finals
  embed_kernel<<<4096, 64, 0, stream>>>(targets, dec_emb, X, 1);
  for (int l = 0; l < 3; l++) {
    gemm_mfma<<<dim3(8, 32), 256, 0, stream>>>(X, Wpk + (long)(3 + l) * NG * HH,
                                               bpk + (3 + l) * NG, G, NG, nullptr);
    lstm_unit<<<64, 1024, 0, stream>>>(G, WT + (long)(3 + l) * HH * NG,
                                       hst + (long)l * BB * HH, HH,
                                       cst + (long)l * BB * HH, HH,
                                       X, hsc, csc);
  }

  // FC head (split-bf16 MFMA) + fused per-64-col argmax, then finalize
  gemm_mfma<<<dim3(250, 32), 256, 0, stream>>>(X, fc_W, fc_b, out0, VV, amax);
  argmax_fin<<<4096, 64, 0, stream>>>(amax, out1, 500);
}